// Round 1
// baseline (72.881 us; speedup 1.0000x reference)
//
#include <hip/hip_runtime.h>

// ---------------------------------------------------------------------------
// EfficentLePE: per window w (B=8 x 16 windows of [128 rows x 8 cols]), head h:
//   A[h] = softmax_e( SCALE * sum_n K[n,d] V[n,e] )          (16x16)
//   out[n,e] = sum_d Q[n,d] A[h][d,e] + depthwise3x3(Q)[n,e]
// Layout: token n = row*8 + wl; global l = row*128 + wb*8 + wl; channel c=h*16+d.
// ---------------------------------------------------------------------------

static constexpr int BB   = 8;
static constexpr int RES  = 128;
static constexpr int DIM  = 128;
static constexpr int WSP  = 8;
static constexpr int L    = RES * RES;        // 16384
static constexpr int NWIN = BB * (RES / WSP); // 128 windows
static constexpr float SCALE = 0.25f;         // HD^-0.5, HD=16
static constexpr int S1 = 4;                  // K1: token splits (32 rows each)
static constexpr int S2 = 8;                  // K2: row splits  (16 rows each)

#define GLD_LDS16(g, l)                                                        \
  __builtin_amdgcn_global_load_lds(                                            \
      (const __attribute__((address_space(1))) void*)(const void*)(g),         \
      (__attribute__((address_space(3))) void*)(l), 16, 0, 0)

// ---------------------------------------------------------------------------
// Kernel 1: partial K^T V per (window, token-split). Writes [blk][h][d][e]
// partial Gram matrices (no scale/softmax yet) to ws.
// ---------------------------------------------------------------------------
__global__ __launch_bounds__(256, 2) void kt_kv_kernel(
    const float* __restrict__ Kg, const float* __restrict__ Vg,
    float* __restrict__ part) {
  __shared__ float K_lds[64 * 128];  // 32 KB (64 tokens x 128 ch)
  __shared__ float V_lds[64 * 128];  // 32 KB

  const int blk = blockIdx.x;        // w*S1 + s
  const int w = blk / S1, s = blk % S1;
  const int b = w >> 4, wb = w & 15;
  const int t = threadIdx.x;
  const int wave = t >> 6, lane = t & 63;

  // accumulator mapping: head h_ (8) x d-quad dq (4) x e-pair ep (8) = 256 thr
  const int h_ = t >> 5;
  const int dq = (t >> 3) & 3;
  const int ep = t & 7;
  const int kaddr = h_ * 16 + dq * 4;
  const int vaddr = h_ * 16 + ep * 2;

  const size_t win_base = (size_t)(b * L + wb * WSP) * DIM;

  float a00 = 0.f, a01 = 0.f, a10 = 0.f, a11 = 0.f;
  float a20 = 0.f, a21 = 0.f, a30 = 0.f, a31 = 0.f;

  for (int tile = 0; tile < 4; ++tile) {
    const int r0 = s * 32 + tile * 8;  // first row of this 8-row tile
    // stage 8 rows x (K,V): 64 x 1KB chunks, wave-uniform LDS dest
    for (int i = 0; i < 16; ++i) {
      const int idx = wave * 16 + i;     // 0..63
      const int m   = idx >> 5;          // 0=K, 1=V
      const int rr  = (idx >> 2) & 7;    // row within tile
      const int kk  = idx & 3;           // 1KB chunk within row
      const float* src = (m ? Vg : Kg) + win_base +
                         (size_t)(r0 + rr) * RES * DIM + kk * 256 + lane * 4;
      float* dst = (m ? V_lds : K_lds) + rr * 1024 + kk * 256;
      GLD_LDS16(src, dst);
    }
    __syncthreads();
#pragma unroll 4
    for (int n = 0; n < 64; ++n) {
      const float4 k4 = *reinterpret_cast<const float4*>(&K_lds[n * 128 + kaddr]);
      const float2 v2 = *reinterpret_cast<const float2*>(&V_lds[n * 128 + vaddr]);
      a00 += k4.x * v2.x; a01 += k4.x * v2.y;
      a10 += k4.y * v2.x; a11 += k4.y * v2.y;
      a20 += k4.z * v2.x; a21 += k4.z * v2.y;
      a30 += k4.w * v2.x; a31 += k4.w * v2.y;
    }
    __syncthreads();
  }

  // write partials: layout [blk][h_*256 + d*16 + e]
  float* p = part + (size_t)blk * 2048 + h_ * 256 + ep * 2;
  *reinterpret_cast<float2*>(&p[(dq * 4 + 0) * 16]) = make_float2(a00, a01);
  *reinterpret_cast<float2*>(&p[(dq * 4 + 1) * 16]) = make_float2(a10, a11);
  *reinterpret_cast<float2*>(&p[(dq * 4 + 2) * 16]) = make_float2(a20, a21);
  *reinterpret_cast<float2*>(&p[(dq * 4 + 3) * 16]) = make_float2(a30, a31);
}

// ---------------------------------------------------------------------------
// Kernel 2: reduce partials + softmax, then out = Q*A + LePE(conv3x3) for a
// 16-row slab of one window.
// ---------------------------------------------------------------------------
__device__ __forceinline__ float4 conv_quad(const float* __restrict__ Qg,
                                            const float* q_lds, size_t win_base,
                                            int r0, int lrr, int wl, int c0) {
  float4 z = make_float4(0.f, 0.f, 0.f, 0.f);
  if ((unsigned)wl >= 8u) return z;                       // width pad
  if ((unsigned)lrr < 16u)                                 // in-slab: LDS
    return *reinterpret_cast<const float4*>(&q_lds[lrr * 1024 + wl * 128 + c0]);
  const int h = r0 + lrr;                                 // halo row
  if ((unsigned)h >= 128u) return z;                      // window/vertical pad
  return *reinterpret_cast<const float4*>(
      &Qg[win_base + (size_t)h * RES * DIM + wl * DIM + c0]);
}

__global__ __launch_bounds__(256, 2) void attn_lepe_kernel(
    const float* __restrict__ Qg, const float* __restrict__ part,
    const float* __restrict__ cw, const float* __restrict__ cb,
    float* __restrict__ outp) {
  __shared__ float q_lds[16 * 1024];  // 64 KB: 16 rows x 8 wl x 128 ch
  __shared__ float A_sm[2048];        // softmaxed A: [h][d][e]
  __shared__ float lg[2048];          // raw logits

  const int blk = blockIdx.x;         // w*S2 + s2
  const int w = blk / S2, s2 = blk % S2;
  const int b = w >> 4, wb = w & 15;
  const int t = threadIdx.x;
  const int wave = t >> 6, lane = t & 63;
  const size_t win_base = (size_t)(b * L + wb * WSP) * DIM;
  const int r0 = s2 * 16;

  // 1) issue async Q slab staging (overlaps with partial reduction below)
  for (int i = 0; i < 16; ++i) {
    const int idx = wave * 16 + i;  // 0..63 = lr*4 + kk
    const int lr = idx >> 2, kk = idx & 3;
    const float* src = Qg + win_base + (size_t)(r0 + lr) * RES * DIM +
                       kk * 256 + lane * 4;
    float* dst = q_lds + lr * 1024 + kk * 256;
    GLD_LDS16(src, dst);
  }

  // 2) reduce the S1 partials -> scaled logits in LDS
  {
    const float* pw = part + (size_t)w * (S1 * 2048);
#pragma unroll
    for (int r = 0; r < 8; ++r) {
      const int idx = r * 256 + t;
      const float v = pw[idx] + pw[2048 + idx] + pw[4096 + idx] + pw[6144 + idx];
      lg[idx] = v * SCALE;
    }
  }
  __syncthreads();  // logits ready (also drains Q staging)

  // 3) softmax over e (rows = h*16+d, 128 rows)
  if (t < 128) {
    const float* row = &lg[t * 16];
    float4 a0 = *reinterpret_cast<const float4*>(row + 0);
    float4 a1 = *reinterpret_cast<const float4*>(row + 4);
    float4 a2 = *reinterpret_cast<const float4*>(row + 8);
    float4 a3 = *reinterpret_cast<const float4*>(row + 12);
    float m = fmaxf(fmaxf(fmaxf(a0.x, a0.y), fmaxf(a0.z, a0.w)),
                    fmaxf(fmaxf(fmaxf(a1.x, a1.y), fmaxf(a1.z, a1.w)),
                          fmaxf(fmaxf(fmaxf(a2.x, a2.y), fmaxf(a2.z, a2.w)),
                                fmaxf(fmaxf(a3.x, a3.y), fmaxf(a3.z, a3.w)))));
    a0.x = __expf(a0.x - m); a0.y = __expf(a0.y - m);
    a0.z = __expf(a0.z - m); a0.w = __expf(a0.w - m);
    a1.x = __expf(a1.x - m); a1.y = __expf(a1.y - m);
    a1.z = __expf(a1.z - m); a1.w = __expf(a1.w - m);
    a2.x = __expf(a2.x - m); a2.y = __expf(a2.y - m);
    a2.z = __expf(a2.z - m); a2.w = __expf(a2.w - m);
    a3.x = __expf(a3.x - m); a3.y = __expf(a3.y - m);
    a3.z = __expf(a3.z - m); a3.w = __expf(a3.w - m);
    const float s = a0.x + a0.y + a0.z + a0.w + a1.x + a1.y + a1.z + a1.w +
                    a2.x + a2.y + a2.z + a2.w + a3.x + a3.y + a3.z + a3.w;
    const float rinv = 1.0f / s;
    a0.x *= rinv; a0.y *= rinv; a0.z *= rinv; a0.w *= rinv;
    a1.x *= rinv; a1.y *= rinv; a1.z *= rinv; a1.w *= rinv;
    a2.x *= rinv; a2.y *= rinv; a2.z *= rinv; a2.w *= rinv;
    a3.x *= rinv; a3.y *= rinv; a3.z *= rinv; a3.w *= rinv;
    float* d = &A_sm[t * 16];
    *reinterpret_cast<float4*>(d + 0)  = a0;
    *reinterpret_cast<float4*>(d + 4)  = a1;
    *reinterpret_cast<float4*>(d + 8)  = a2;
    *reinterpret_cast<float4*>(d + 12) = a3;
  }
  __syncthreads();

  // 4) per-thread preload: A column-quad (64 VGPR) + conv weights (36) + bias
  const int cq = t & 31, tg = t >> 5;
  const int h_ = cq >> 2;             // head
  const int e0 = (cq & 3) * 4;        // e-quad within head
  const int c0 = cq * 4;              // global channel quad = h_*16 + e0
  float4 Acol[16];
#pragma unroll
  for (int d = 0; d < 16; ++d)
    Acol[d] = *reinterpret_cast<const float4*>(&A_sm[h_ * 256 + d * 16 + e0]);
  float4 wgt[9];
#pragma unroll
  for (int tap = 0; tap < 9; ++tap) {
    wgt[tap].x = cw[(c0 + 0) * 9 + tap];
    wgt[tap].y = cw[(c0 + 1) * 9 + tap];
    wgt[tap].z = cw[(c0 + 2) * 9 + tap];
    wgt[tap].w = cw[(c0 + 3) * 9 + tap];
  }
  const float4 bias = *reinterpret_cast<const float4*>(&cb[c0]);

#define ACC(qs, d)                                                             \
  o.x += (qs) * Acol[d].x; o.y += (qs) * Acol[d].y;                            \
  o.z += (qs) * Acol[d].z; o.w += (qs) * Acol[d].w;

  // 5) main loop: 2 rows x 8 cols per thread
  for (int rsel = 0; rsel < 2; ++rsel) {
    const int lr = tg + rsel * 8;   // local row 0..15
    const int h = r0 + lr;          // global row
#pragma unroll
    for (int wl = 0; wl < 8; ++wl) {
      float4 o = bias;
      // LePE conv 3x3 (depthwise, SAME padding within window)
#pragma unroll
      for (int dy = -1; dy <= 1; ++dy) {
#pragma unroll
        for (int dx = -1; dx <= 1; ++dx) {
          const float4 qq = conv_quad(Qg, q_lds, win_base, r0, lr + dy, wl + dx, c0);
          const int tap = (dy + 1) * 3 + (dx + 1);
          o.x += qq.x * wgt[tap].x; o.y += qq.y * wgt[tap].y;
          o.z += qq.z * wgt[tap].z; o.w += qq.w * wgt[tap].w;
        }
      }
      // Q . A   (16 d-values of this head)
      const float* qr = &q_lds[lr * 1024 + wl * 128 + h_ * 16];
      const float4 q0 = *reinterpret_cast<const float4*>(qr + 0);
      const float4 q1 = *reinterpret_cast<const float4*>(qr + 4);
      const float4 q2 = *reinterpret_cast<const float4*>(qr + 8);
      const float4 q3 = *reinterpret_cast<const float4*>(qr + 12);
      ACC(q0.x, 0)  ACC(q0.y, 1)  ACC(q0.z, 2)  ACC(q0.w, 3)
      ACC(q1.x, 4)  ACC(q1.y, 5)  ACC(q1.z, 6)  ACC(q1.w, 7)
      ACC(q2.x, 8)  ACC(q2.y, 9)  ACC(q2.z, 10) ACC(q2.w, 11)
      ACC(q3.x, 12) ACC(q3.y, 13) ACC(q3.z, 14) ACC(q3.w, 15)

      float* dst = outp + win_base + (size_t)h * RES * DIM + wl * DIM + c0;
      *reinterpret_cast<float4*>(dst) = o;
    }
  }
#undef ACC
}

// ---------------------------------------------------------------------------
extern "C" void kernel_launch(void* const* d_in, const int* in_sizes, int n_in,
                              void* d_out, int out_size, void* d_ws,
                              size_t ws_size, hipStream_t stream) {
  const float* qkv = (const float*)d_in[0];
  const float* cw  = (const float*)d_in[1];
  const float* cb  = (const float*)d_in[2];
  const float* Qg = qkv;
  const float* Kg = qkv + (size_t)BB * L * DIM;       // + 16777216
  const float* Vg = Kg + (size_t)BB * L * DIM;
  float* part = (float*)d_ws;                         // needs 4 MB
  float* outp = (float*)d_out;

  kt_kv_kernel<<<NWIN * S1, 256, 0, stream>>>(Kg, Vg, part);
  attn_lepe_kernel<<<NWIN * S2, 256, 0, stream>>>(Qg, part, cw, cb, outp);
}

// Round 2
// 58.359 us; speedup vs baseline: 1.2488x; 1.2488x over previous
//
#include <hip/hip_runtime.h>

// ---------------------------------------------------------------------------
// EfficentLePE: per window w (B=8 x 16 windows of [128 rows x 8 cols]), head h:
//   A[h] = softmax_e( SCALE * sum_n K[n,d] V[n,e] )          (16x16)
//   out[n,e] = sum_d Q[n,d] A[h][d,e] + depthwise3x3(Q)[n,e]
// token n = row*8 + wl; global l = row*128 + wb*8 + wl; channel c = h*16+d.
// ---------------------------------------------------------------------------

static constexpr int BB   = 8;
static constexpr int RES  = 128;
static constexpr int DIM  = 128;
static constexpr int WSP  = 8;
static constexpr int L    = RES * RES;        // 16384
static constexpr int NWIN = BB * (RES / WSP); // 128 windows
static constexpr float SCALE = 0.25f;         // HD^-0.5, HD=16
static constexpr int S1 = 4;                  // K1: token splits (32 rows each)
static constexpr int S2 = 8;                  // K2: row splits  (16 rows each)

#define GLD_LDS16(g, l)                                                        \
  __builtin_amdgcn_global_load_lds(                                            \
      (const __attribute__((address_space(1))) void*)(const void*)(g),         \
      (__attribute__((address_space(3))) void*)(l), 16, 0, 0)

// ---------------------------------------------------------------------------
// Kernel 1: partial K^T V per (window, token-split), double-buffered 4-row
// tiles. Writes [blk][h][d][e] partial Gram matrices to ws.
// ---------------------------------------------------------------------------
__global__ __launch_bounds__(256, 2) void kt_kv_kernel(
    const float* __restrict__ Kg, const float* __restrict__ Vg,
    float* __restrict__ part) {
  __shared__ float K_lds[2][4 * 1024];  // 2 x 16 KB (4 rows x 8 wl x 128 ch)
  __shared__ float V_lds[2][4 * 1024];  // 2 x 16 KB

  const int blk = blockIdx.x;        // w*S1 + s
  const int w = blk / S1, s = blk % S1;
  const int b = w >> 4, wb = w & 15;
  const int t = threadIdx.x;
  const int wave = t >> 6, lane = t & 63;

  // accumulator mapping: head h_ (8) x d-quad dq (4) x e-pair ep (8) = 256 thr
  const int h_ = t >> 5;
  const int dq = (t >> 3) & 3;
  const int ep = t & 7;
  const int kaddr = h_ * 16 + dq * 4;
  const int vaddr = h_ * 16 + ep * 2;

  const size_t win_base = (size_t)(b * L + wb * WSP) * DIM;

  float a00 = 0.f, a01 = 0.f, a10 = 0.f, a11 = 0.f;
  float a20 = 0.f, a21 = 0.f, a30 = 0.f, a31 = 0.f;

  auto stage = [&](int tile, int buf) {
    const int r0 = s * 32 + tile * 4;  // first row of this 4-row tile
    for (int i = 0; i < 8; ++i) {
      const int idx = wave * 8 + i;    // 0..31
      const int m   = idx >> 4;        // 0=K, 1=V
      const int rr  = (idx >> 2) & 3;  // row within tile
      const int kk  = idx & 3;         // 1KB chunk within row
      const float* src = (m ? Vg : Kg) + win_base +
                         (size_t)(r0 + rr) * RES * DIM + kk * 256 + lane * 4;
      float* dst = (m ? &V_lds[buf][0] : &K_lds[buf][0]) + rr * 1024 + kk * 256;
      GLD_LDS16(src, dst);
    }
  };

  stage(0, 0);
  __syncthreads();

  for (int tt = 0; tt < 8; ++tt) {
    const int cur = tt & 1;
    if (tt < 7) stage(tt + 1, cur ^ 1);
    const float* Kb = &K_lds[cur][0];
    const float* Vb = &V_lds[cur][0];
#pragma unroll 4
    for (int n = 0; n < 32; ++n) {
      const float4 k4 = *reinterpret_cast<const float4*>(&Kb[n * 128 + kaddr]);
      const float2 v2 = *reinterpret_cast<const float2*>(&Vb[n * 128 + vaddr]);
      a00 += k4.x * v2.x; a01 += k4.x * v2.y;
      a10 += k4.y * v2.x; a11 += k4.y * v2.y;
      a20 += k4.z * v2.x; a21 += k4.z * v2.y;
      a30 += k4.w * v2.x; a31 += k4.w * v2.y;
    }
    __syncthreads();
  }

  // write partials: layout [blk][h_*256 + d*16 + e]
  float* p = part + (size_t)blk * 2048 + h_ * 256 + ep * 2;
  *reinterpret_cast<float2*>(&p[(dq * 4 + 0) * 16]) = make_float2(a00, a01);
  *reinterpret_cast<float2*>(&p[(dq * 4 + 1) * 16]) = make_float2(a10, a11);
  *reinterpret_cast<float2*>(&p[(dq * 4 + 2) * 16]) = make_float2(a20, a21);
  *reinterpret_cast<float2*>(&p[(dq * 4 + 3) * 16]) = make_float2(a30, a31);
}

// ---------------------------------------------------------------------------
// Kernel 2: reduce partials + in-register softmax, then out = Q*A + LePE
// (depthwise 3x3) for a 16-row slab of one window. Q staged with 1-row halos
// (18 rows, zero-filled at image edges) so the conv loop is branch-free.
// ---------------------------------------------------------------------------
__global__ __launch_bounds__(256, 2) void attn_lepe_kernel(
    const float* __restrict__ Qg, const float* __restrict__ part,
    const float* __restrict__ cw, const float* __restrict__ cb,
    float* __restrict__ outp) {
  __shared__ float q_lds[18 * 1024];  // 72 KB: rows r0-1 .. r0+16
  __shared__ float A_sm[2048];        // softmaxed A: [h][d][e]

  const int blk = blockIdx.x;         // w*S2 + s2
  const int w = blk / S2, s2 = blk % S2;
  const int b = w >> 4, wb = w & 15;
  const int t = threadIdx.x;
  const int wave = t >> 6, lane = t & 63;
  const size_t win_base = (size_t)(b * L + wb * WSP) * DIM;
  const int r0 = s2 * 16;

  // 1) issue async Q slab staging (18 rows incl. halos), zero-fill off-image
  for (int i = 0; i < 18; ++i) {
    const int idx = wave * 18 + i;   // 0..71
    const int hr = idx >> 2, kk = idx & 3;
    const int g = r0 - 1 + hr;       // global image row
    float* dst = q_lds + hr * 1024 + kk * 256;
    if ((unsigned)g < 128u) {
      const float* src = Qg + win_base + (size_t)g * RES * DIM + kk * 256 +
                         lane * 4;
      GLD_LDS16(src, dst);
    } else {
      *reinterpret_cast<float4*>(dst + lane * 4) =
          make_float4(0.f, 0.f, 0.f, 0.f);
    }
  }

  // 2) reduce S1 partials + softmax fully in registers.
  //    thread t owns 8 contiguous logits = half of row (t>>1); pair via shfl.
  {
    const float* pw = part + (size_t)w * (S1 * 2048) + t * 8;
    float4 u0, u1;
    {
      const float4 a0 = *reinterpret_cast<const float4*>(pw);
      const float4 b0 = *reinterpret_cast<const float4*>(pw + 2048);
      const float4 c0 = *reinterpret_cast<const float4*>(pw + 4096);
      const float4 d0 = *reinterpret_cast<const float4*>(pw + 6144);
      u0.x = (a0.x + b0.x + c0.x + d0.x) * SCALE;
      u0.y = (a0.y + b0.y + c0.y + d0.y) * SCALE;
      u0.z = (a0.z + b0.z + c0.z + d0.z) * SCALE;
      u0.w = (a0.w + b0.w + c0.w + d0.w) * SCALE;
      const float4 a1 = *reinterpret_cast<const float4*>(pw + 4);
      const float4 b1 = *reinterpret_cast<const float4*>(pw + 2052);
      const float4 c1 = *reinterpret_cast<const float4*>(pw + 4100);
      const float4 d1 = *reinterpret_cast<const float4*>(pw + 6148);
      u1.x = (a1.x + b1.x + c1.x + d1.x) * SCALE;
      u1.y = (a1.y + b1.y + c1.y + d1.y) * SCALE;
      u1.z = (a1.z + b1.z + c1.z + d1.z) * SCALE;
      u1.w = (a1.w + b1.w + c1.w + d1.w) * SCALE;
    }
    float m = fmaxf(fmaxf(fmaxf(u0.x, u0.y), fmaxf(u0.z, u0.w)),
                    fmaxf(fmaxf(u1.x, u1.y), fmaxf(u1.z, u1.w)));
    m = fmaxf(m, __shfl_xor(m, 1));
    u0.x = __expf(u0.x - m); u0.y = __expf(u0.y - m);
    u0.z = __expf(u0.z - m); u0.w = __expf(u0.w - m);
    u1.x = __expf(u1.x - m); u1.y = __expf(u1.y - m);
    u1.z = __expf(u1.z - m); u1.w = __expf(u1.w - m);
    float ssum = u0.x + u0.y + u0.z + u0.w + u1.x + u1.y + u1.z + u1.w;
    ssum += __shfl_xor(ssum, 1);
    const float rinv = 1.0f / ssum;
    u0.x *= rinv; u0.y *= rinv; u0.z *= rinv; u0.w *= rinv;
    u1.x *= rinv; u1.y *= rinv; u1.z *= rinv; u1.w *= rinv;
    *reinterpret_cast<float4*>(&A_sm[t * 8 + 0]) = u0;
    *reinterpret_cast<float4*>(&A_sm[t * 8 + 4]) = u1;
  }
  __syncthreads();  // A_sm ready; Q staging drained

  // 3) per-thread preload: A column-quad (64 VGPR) + conv weights + bias
  const int cq = t & 31, tg = t >> 5;
  const int h_ = cq >> 2;             // head
  const int e0 = (cq & 3) * 4;        // e-quad within head
  const int c0 = cq * 4;              // global channel quad = h_*16 + e0
  float4 Acol[16];
#pragma unroll
  for (int d = 0; d < 16; ++d)
    Acol[d] = *reinterpret_cast<const float4*>(&A_sm[h_ * 256 + d * 16 + e0]);
  float4 wgt[9];
#pragma unroll
  for (int tap = 0; tap < 9; ++tap) {
    wgt[tap].x = cw[(c0 + 0) * 9 + tap];
    wgt[tap].y = cw[(c0 + 1) * 9 + tap];
    wgt[tap].z = cw[(c0 + 2) * 9 + tap];
    wgt[tap].w = cw[(c0 + 3) * 9 + tap];
  }
  const float4 bias = *reinterpret_cast<const float4*>(&cb[c0]);

#define ACC(qs, d)                                                             \
  o.x += (qs) * Acol[d].x; o.y += (qs) * Acol[d].y;                            \
  o.z += (qs) * Acol[d].z; o.w += (qs) * Acol[d].w;
#define CONV(cv, tap)                                                          \
  o.x += cv[dy].x * wgt[tap].x; o.y += cv[dy].y * wgt[tap].y;                  \
  o.z += cv[dy].z * wgt[tap].z; o.w += cv[dy].w * wgt[tap].w;

  const float4 zero4 = make_float4(0.f, 0.f, 0.f, 0.f);

  // 4) main loop: 2 rows x 8 cols per thread, rolling 3-column conv window
  for (int rsel = 0; rsel < 2; ++rsel) {
    const int lr = tg + rsel * 8;            // local row 0..15
    const float* rbase = q_lds + lr * 1024;  // hr = lr  <=> image row r0+lr-1
    float4 cL[3], cC[3];
#pragma unroll
    for (int dy = 0; dy < 3; ++dy) {
      cL[dy] = zero4;  // col -1 (window pad)
      cC[dy] = *reinterpret_cast<const float4*>(&rbase[dy * 1024 + c0]);
    }
#pragma unroll
    for (int wl = 0; wl < 8; ++wl) {
      float4 cR[3];
#pragma unroll
      for (int dy = 0; dy < 3; ++dy)
        cR[dy] = (wl < 7)
                     ? *reinterpret_cast<const float4*>(
                           &rbase[dy * 1024 + (wl + 1) * 128 + c0])
                     : zero4;
      float4 o = bias;
#pragma unroll
      for (int dy = 0; dy < 3; ++dy) {
        CONV(cL, dy * 3 + 0)
        CONV(cC, dy * 3 + 1)
        CONV(cR, dy * 3 + 2)
      }
      // Q . A   (16 d-values of this head; Q row = image row r0+lr -> hr lr+1)
      const float* qr = &rbase[1024 + wl * 128 + h_ * 16];
      const float4 q0 = *reinterpret_cast<const float4*>(qr + 0);
      const float4 q1 = *reinterpret_cast<const float4*>(qr + 4);
      const float4 q2 = *reinterpret_cast<const float4*>(qr + 8);
      const float4 q3 = *reinterpret_cast<const float4*>(qr + 12);
      ACC(q0.x, 0)  ACC(q0.y, 1)  ACC(q0.z, 2)  ACC(q0.w, 3)
      ACC(q1.x, 4)  ACC(q1.y, 5)  ACC(q1.z, 6)  ACC(q1.w, 7)
      ACC(q2.x, 8)  ACC(q2.y, 9)  ACC(q2.z, 10) ACC(q2.w, 11)
      ACC(q3.x, 12) ACC(q3.y, 13) ACC(q3.z, 14) ACC(q3.w, 15)

      float* dst = outp + win_base + (size_t)(r0 + lr) * RES * DIM +
                   wl * DIM + c0;
      *reinterpret_cast<float4*>(dst) = o;

#pragma unroll
      for (int dy = 0; dy < 3; ++dy) { cL[dy] = cC[dy]; cC[dy] = cR[dy]; }
    }
  }
#undef ACC
#undef CONV
}

// ---------------------------------------------------------------------------
extern "C" void kernel_launch(void* const* d_in, const int* in_sizes, int n_in,
                              void* d_out, int out_size, void* d_ws,
                              size_t ws_size, hipStream_t stream) {
  const float* qkv = (const float*)d_in[0];
  const float* cw  = (const float*)d_in[1];
  const float* cb  = (const float*)d_in[2];
  const float* Qg = qkv;
  const float* Kg = qkv + (size_t)BB * L * DIM;
  const float* Vg = Kg + (size_t)BB * L * DIM;
  float* part = (float*)d_ws;                         // needs 4 MB
  float* outp = (float*)d_out;

  kt_kv_kernel<<<NWIN * S1, 256, 0, stream>>>(Kg, Vg, part);
  attn_lepe_kernel<<<NWIN * S2, 256, 0, stream>>>(Qg, part, cw, cb, outp);
}

// Round 4
// 55.294 us; speedup vs baseline: 1.3181x; 1.0554x over previous
//
#include <hip/hip_runtime.h>

// ---------------------------------------------------------------------------
// EfficentLePE, fully block-local: block = (window w, head-pair g).
// Window = [128 rows x 8 cols] tokens; head h <-> channels [h*16,(h+1)*16).
//   A[h] = softmax_e( SCALE * sum_n K[n,d] V[n,e] )   (16x16)
//   out[n,e] = sum_d Q[n,d] A[h][d,e] + depthwise3x3(Q)[n,e] + bias
// Pass 1 streams K/V channel-slices (16-row tiles, dbuf) -> Gram in regs.
// Block-reduce + softmax -> A_sm. Pass 2 streams Q slices (18-row halo
// tiles, dbuf) -> Q.A + conv + store. No workspace, no grid sync.
// ---------------------------------------------------------------------------

static constexpr int BB   = 8;
static constexpr int RES  = 128;
static constexpr int DIM  = 128;
static constexpr int WSP  = 8;
static constexpr int L    = RES * RES;   // 16384
static constexpr float SCALE = 0.25f;    // HD^-0.5, HD=16

#define GLD_LDS16(g, l)                                                        \
  __builtin_amdgcn_global_load_lds(                                            \
      (const __attribute__((address_space(1))) void*)(const void*)(g),         \
      (__attribute__((address_space(3))) void*)(l), 16, 0, 0)

__global__ __launch_bounds__(256, 2) void fused_lepe(
    const float* __restrict__ Qg, const float* __restrict__ Kg,
    const float* __restrict__ Vg, const float* __restrict__ cw,
    const float* __restrict__ cb, float* __restrict__ outp) {
  // smem map (floats):
  //  pass1: K tiles [0,8192) (2 bufs x 4096), V tiles [8192,16384)
  //  reduce scratch [0,2048)            (after pass1)
  //  pass2: Qbuf0 [0,4608), Qbuf1 [4608,9216)
  //  A_sm  [16384,16896)
  __shared__ float smem[16896];
  float* const A_sm = smem + 16384;

  const int b  = blockIdx.x;            // 0..511
  const int w  = b >> 2, g = b & 3;     // window, head-group (2 heads)
  const int bi = w >> 4, wb = w & 15;   // batch, window-col
  const int t  = threadIdx.x;
  const int wave = t >> 6, lane = t & 63;
  const size_t win_base = (size_t)(bi * L + wb * WSP) * DIM;
  const int ch0 = g * 32;               // first global channel of this group

  // ======== Pass 1: Gram = K^T V for 2 heads, 8 tiles of 16 image rows ====
  // wave-lane accum mapping: h1 = lane>>5 (head), dq=(lane>>3)&3, ep=lane&7
  const int h1 = lane >> 5, dq = (lane >> 3) & 3, ep = lane & 7;
  float a00=0.f,a01=0.f,a10=0.f,a11=0.f,a20=0.f,a21=0.f,a30=0.f,a31=0.f;

  auto stageKV = [&](int tile, int buf) {
    // 32 chunks: mat (K/V) x 16 rows; 8 per wave. Chunk = 8 tokens x 32 ch.
    for (int c = wave; c < 32; c += 4) {
      const int mat = c >> 4, rr = c & 15;
      const int r = tile * 16 + rr;     // image row
      const float* src = (mat ? Vg : Kg) + win_base +
                         (size_t)r * (RES * DIM) + (lane >> 3) * DIM + ch0 +
                         (lane & 7) * 4;
      float* dst = smem + mat * 8192 + buf * 4096 + rr * 256;
      GLD_LDS16(src, dst);
    }
  };

  stageKV(0, 0);
  __syncthreads();
  for (int tt = 0; tt < 8; ++tt) {
    const int cur = tt & 1;
    if (tt < 7) stageKV(tt + 1, cur ^ 1);
    const float* Kb = smem + cur * 4096;
    const float* Vb = smem + 8192 + cur * 4096;
    const int n0 = wave * 32;           // this wave's token quarter of tile
#pragma unroll 4
    for (int n = n0; n < n0 + 32; ++n) {
      const float4 k4 =
          *reinterpret_cast<const float4*>(&Kb[n * 32 + h1 * 16 + dq * 4]);
      const float2 v2 =
          *reinterpret_cast<const float2*>(&Vb[n * 32 + h1 * 16 + ep * 2]);
      a00 += k4.x * v2.x; a01 += k4.x * v2.y;
      a10 += k4.y * v2.x; a11 += k4.y * v2.y;
      a20 += k4.z * v2.x; a21 += k4.z * v2.y;
      a30 += k4.w * v2.x; a31 += k4.w * v2.y;
    }
    __syncthreads();
  }

  // ======== Q-tile staging helper (18 rows incl. halos, zero off-image) ===
  auto stageQ = [&](int tile, int buf) {
    const int r0 = tile * 16;
    float* qb = smem + buf * 4608;
    for (int c = wave; c < 18; c += 4) {
      const int r = r0 - 1 + c;         // image row for buffer row c
      float* dst = qb + c * 256;
      if ((unsigned)r < 128u) {
        const float* src = Qg + win_base + (size_t)r * (RES * DIM) +
                           (lane >> 3) * DIM + ch0 + (lane & 7) * 4;
        GLD_LDS16(src, dst);
      } else {
        *reinterpret_cast<float4*>(dst + lane * 4) =
            make_float4(0.f, 0.f, 0.f, 0.f);
      }
    }
  };

  // issue Q tile 0 into buf1; its latency hides under the reduction below
  stageQ(0, 1);

  // write per-wave Gram partials -> scratch [wave][lane][8]
  {
    float* sc = smem + wave * 512 + lane * 8;
    sc[0]=a00; sc[1]=a01; sc[2]=a10; sc[3]=a11;
    sc[4]=a20; sc[5]=a21; sc[6]=a30; sc[7]=a31;
  }
  __syncthreads();

  // ======== reduce 4 waves + softmax over e -> A_sm[h][d][e] ==============
  {
    const int r  = t >> 3;              // 0..31 = h*16+d
    const int e2 = t & 7;               // e-pair
    const int h = r >> 4, d = r & 15;
    const int f = (h * 32 + (d >> 2) * 8 + e2) * 8 + (d & 3) * 2;
    float v0 = smem[f]     + smem[512 + f]     + smem[1024 + f]     + smem[1536 + f];
    float v1 = smem[f + 1] + smem[512 + f + 1] + smem[1024 + f + 1] + smem[1536 + f + 1];
    v0 *= SCALE; v1 *= SCALE;
    float m = fmaxf(v0, v1);
    m = fmaxf(m, __shfl_xor(m, 1));
    m = fmaxf(m, __shfl_xor(m, 2));
    m = fmaxf(m, __shfl_xor(m, 4));
    v0 = __expf(v0 - m); v1 = __expf(v1 - m);
    float ssum = v0 + v1;
    ssum += __shfl_xor(ssum, 1);
    ssum += __shfl_xor(ssum, 2);
    ssum += __shfl_xor(ssum, 4);
    const float rinv = 1.0f / ssum;
    A_sm[r * 16 + e2 * 2 + 0] = v0 * rinv;
    A_sm[r * 16 + e2 * 2 + 1] = v1 * rinv;
  }
  __syncthreads();   // A_sm visible; scratch free; Q tile 0 drained

  // ======== Pass 2 setup: per-thread A column, conv weights, bias =========
  const int cq   = t & 7;               // channel granule (4 ch) within 32
  const int lr   = (t >> 3) & 15;       // local output row in tile
  const int half = t >> 7;              // wl range: half*4 .. half*4+3
  const int hg = cq >> 2, e0 = (cq & 3) * 4;
  const int cg = ch0 + cq * 4;          // global channel quad base

  float4 Acol[16];
#pragma unroll
  for (int d = 0; d < 16; ++d)
    Acol[d] = *reinterpret_cast<const float4*>(&A_sm[(hg * 16 + d) * 16 + e0]);
  float4 wgt[9];
#pragma unroll
  for (int tap = 0; tap < 9; ++tap) {
    wgt[tap].x = cw[(cg + 0) * 9 + tap];
    wgt[tap].y = cw[(cg + 1) * 9 + tap];
    wgt[tap].z = cw[(cg + 2) * 9 + tap];
    wgt[tap].w = cw[(cg + 3) * 9 + tap];
  }
  const float4 bias = *reinterpret_cast<const float4*>(&cb[cg]);

#define ACC(qs, d)                                                             \
  o.x += (qs) * Acol[d].x; o.y += (qs) * Acol[d].y;                            \
  o.z += (qs) * Acol[d].z; o.w += (qs) * Acol[d].w;

  // ======== Pass 2 main loop: 8 tiles of 16 rows, double-buffered =========
  int buf = 1;
  for (int tile = 0; tile < 8; ++tile) {
    if (tile < 7) stageQ(tile + 1, buf ^ 1);
    const float* Qb = smem + buf * 4608;
    const int r0 = tile * 16;
    const int w0 = half * 4;

    float4 cL[3], cC[3], cR[3];
    auto ldcol = [&](int cidx, float4* dstv) {
#pragma unroll
      for (int dy = 0; dy < 3; ++dy)
        dstv[dy] = ((unsigned)cidx < 8u)
                       ? *reinterpret_cast<const float4*>(
                             &Qb[((lr + dy) * 8 + cidx) * 32 + cq * 4])
                       : make_float4(0.f, 0.f, 0.f, 0.f);
    };
    ldcol(w0 - 1, cL);
    ldcol(w0, cC);

#pragma unroll
    for (int k = 0; k < 4; ++k) {
      const int wl = w0 + k;
      ldcol(wl + 1, cR);
      float4 o = bias;
#pragma unroll
      for (int dy = 0; dy < 3; ++dy) {
        const int t0 = dy * 3;
        o.x += cL[dy].x * wgt[t0].x + cC[dy].x * wgt[t0+1].x + cR[dy].x * wgt[t0+2].x;
        o.y += cL[dy].y * wgt[t0].y + cC[dy].y * wgt[t0+1].y + cR[dy].y * wgt[t0+2].y;
        o.z += cL[dy].z * wgt[t0].z + cC[dy].z * wgt[t0+1].z + cR[dy].z * wgt[t0+2].z;
        o.w += cL[dy].w * wgt[t0].w + cC[dy].w * wgt[t0+1].w + cR[dy].w * wgt[t0+2].w;
      }
      // attention: Q[token, hg*16..+15] . Acol  (token buffer row = lr+1)
      const float* qr = &Qb[((lr + 1) * 8 + wl) * 32 + hg * 16];
      const float4 q0 = *reinterpret_cast<const float4*>(qr + 0);
      const float4 q1 = *reinterpret_cast<const float4*>(qr + 4);
      const float4 q2 = *reinterpret_cast<const float4*>(qr + 8);
      const float4 q3 = *reinterpret_cast<const float4*>(qr + 12);
      ACC(q0.x, 0)  ACC(q0.y, 1)  ACC(q0.z, 2)  ACC(q0.w, 3)
      ACC(q1.x, 4)  ACC(q1.y, 5)  ACC(q1.z, 6)  ACC(q1.w, 7)
      ACC(q2.x, 8)  ACC(q2.y, 9)  ACC(q2.z, 10) ACC(q2.w, 11)
      ACC(q3.x, 12) ACC(q3.y, 13) ACC(q3.z, 14) ACC(q3.w, 15)

      float* dst = outp + win_base + (size_t)(r0 + lr) * (RES * DIM) +
                   wl * DIM + cg;
      *reinterpret_cast<float4*>(dst) = o;

#pragma unroll
      for (int dy = 0; dy < 3; ++dy) { cL[dy] = cC[dy]; cC[dy] = cR[dy]; }
    }
    __syncthreads();
    buf ^= 1;
  }
#undef ACC
}

// ---------------------------------------------------------------------------
extern "C" void kernel_launch(void* const* d_in, const int* in_sizes, int n_in,
                              void* d_out, int out_size, void* d_ws,
                              size_t ws_size, hipStream_t stream) {
  const float* qkv = (const float*)d_in[0];
  const float* cw  = (const float*)d_in[1];
  const float* cb  = (const float*)d_in[2];
  const float* Qg = qkv;
  const float* Kg = qkv + (size_t)BB * L * DIM;
  const float* Vg = Kg + (size_t)BB * L * DIM;
  float* outp = (float*)d_out;

  fused_lepe<<<512, 256, 0, stream>>>(Qg, Kg, Vg, cw, cb, outp);
}